// Round 22
// baseline (138.964 us; speedup 1.0000x reference)
//
#include <hip/hip_runtime.h>
#include <math.h>

#define NEG_SLOPE 0.2f

typedef float  f32x4 __attribute__((ext_vector_type(4)));
typedef short  s16x8 __attribute__((ext_vector_type(8)));

__device__ __forceinline__ unsigned short bfr(float a){
  unsigned u = __float_as_uint(a);
  return (unsigned short)((u + 0x7FFFu + ((u>>16)&1u)) >> 16);
}
__device__ __forceinline__ float bf2f(unsigned short s){
  return __uint_as_float(((unsigned)s)<<16);
}
__device__ __forceinline__ ushort4 packf4(float4 v){
  ushort4 r; r.x=bfr(v.x); r.y=bfr(v.y); r.z=bfr(v.z); r.w=bfr(v.w); return r;
}

// f32 -> int8 linear, q = rint(v*128), clamp ±127 (|h| < 1 by construction)
__device__ __forceinline__ signed char q8(float v){
  int q = __float2int_rn(v * 128.f);
  q = q > 127 ? 127 : (q < -127 ? -127 : q);
  return (signed char)q;
}

// ---------------- block 0: wvec + zero bcnt; blocks 1-8: weight pre-pack (B-frag order)
__global__ void k_wvec_pack(const float* __restrict__ Wsrc, const float* __restrict__ Wdst,
                            const float* __restrict__ Wmain,
                            const float* __restrict__ att_src, const float* __restrict__ att_dst,
                            float* __restrict__ wvec, int* __restrict__ bcnt,
                            unsigned short* __restrict__ pw, unsigned short* __restrict__ ps){
  int tid = threadIdx.x;           // 512 threads
  if (blockIdx.x == 0){
    if (tid < 128) bcnt[tid] = 0;
    int v = tid >> 6, t = tid & 63;
    const float* M = (v<4) ? (Wsrc + v*4096) : (Wdst + (v-4)*4096);
    const float* a = (v<4) ? (att_src + v*64) : (att_dst + (v-4)*64);
    float s = 0.f;
    for (int k=0;k<64;++k) s += M[t*64+k]*a[k];
    wvec[v*64+t] = s;
  } else {
    int vv = (blockIdx.x-1)*512 + tid;     // 4096 slots, 2048 jobs
    if (vv < 2048){
      int l = vv & 63, u = vv >> 6;
      int ct = u & 3, ks = (u>>2)&1, g = u>>3;
      int col = ct*16 + (l&15);
      int r0  = ks*32 + (l>>4)*8;
      #pragma unroll
      for (int j=0;j<8;++j){
        pw[vv*8+j] = bfr(Wmain[g*4096 + (r0+j)*64 + col]);
        ps[vv*8+j] = bfr(Wsrc [g*4096 + (r0+j)*64 + col]);
      }
    }
  }
}

// ---------------- pack x->bf16, h->int8; alphas = h.wvec[v]; + fused BUCKET histogram
__global__ __launch_bounds__(256) void k_pack(
    const float* __restrict__ x, const float* __restrict__ h,
    const float* __restrict__ wvec, const int* __restrict__ ei,
    unsigned short* __restrict__ xb, signed char* __restrict__ h8,
    float* __restrict__ alphas, int* __restrict__ bcnt, int shift, int N, int E){
  __shared__ float hl[32*65];
  __shared__ float wl[8*65];
  __shared__ int   cb[128];
  int tid = threadIdx.x;
  int nbase = blockIdx.x*32;
  int nlim = min(32, N-nbase);
  int cnt = nlim*16;
  if (tid < 128) cb[tid] = 0;
  {
    const float4* hsrc = (const float4*)(h + (size_t)nbase*64);
    const float4* xsrc = (const float4*)(x + (size_t)nbase*64);
    char4* hdst = (char4*)(h8 + (size_t)nbase*64);
    ushort4* xdst = (ushort4*)(xb + (size_t)nbase*64);
    for (int i=tid; i<cnt; i+=256){
      float4 v = hsrc[i];
      int n = i>>4, t4 = (i&15)*4;
      float* d = hl + n*65 + t4;
      d[0]=v.x; d[1]=v.y; d[2]=v.z; d[3]=v.w;
      hdst[i] = make_char4(q8(v.x), q8(v.y), q8(v.z), q8(v.w));
      xdst[i] = packf4(xsrc[i]);
    }
    for (int i=tid; i<512; i+=256) wl[(i>>6)*65 + (i&63)] = wvec[i];
  }
  __syncthreads();
  int v = tid & 7, n = tid >> 3;     // 32 rows x 8 vecs
  if (n < nlim){
    const float* hp = hl + n*65;
    const float* wp = wl + v*65;
    float s = 0.f;
    #pragma unroll
    for (int t=0;t<64;++t) s += hp[t]*wp[t];
    alphas[(size_t)(nbase+n)*8 + v] = s;
  }
  // ---- fused bucket histogram (LDS-privatized, 128 global atomics per block)
  int Q = E >> 2;
  const int4* d4 = (const int4*)(ei + E);
  long gs = (long)gridDim.x*256;
  for (long q=(long)blockIdx.x*256+tid; q<Q; q+=gs){
    int4 d = d4[q];
    atomicAdd(&cb[d.x>>shift],1); atomicAdd(&cb[d.y>>shift],1);
    atomicAdd(&cb[d.z>>shift],1); atomicAdd(&cb[d.w>>shift],1);
  }
  int tail = E - (Q<<2);
  if (blockIdx.x == 0 && tid < tail) atomicAdd(&cb[ei[E+(Q<<2)+tid]>>shift],1);
  __syncthreads();
  if (tid < 128 && cb[tid]) atomicAdd(&bcnt[tid], cb[tid]);
}

// ---------------- scan <=128 bucket counts -> bbase + bfill cursors
__global__ void k_bscan(const int* __restrict__ bcnt, int* __restrict__ bbase,
                        int* __restrict__ bfill, int* __restrict__ rowptr,
                        int nbuck, int N, int E){
  __shared__ int s[128];
  int tid = threadIdx.x;             // 128 threads
  int x = (tid<nbuck) ? bcnt[tid] : 0;
  s[tid] = x;
  __syncthreads();
  for (int off=1; off<128; off<<=1){
    int t = (tid>=off) ? s[tid-off] : 0;
    __syncthreads();
    s[tid] += t;
    __syncthreads();
  }
  if (tid<nbuck){ int e = s[tid]-x; bbase[tid]=e; bfill[tid]=e; }
  if (tid==0){ bbase[nbuck]=E; rowptr[N]=E; }
}

// ---------------- phase A: LDS-binned coarse sort; per-edge src-alpha gather+bf16 pack.
// The alphas[src] scatter-gather moves HERE (391 blocks, 8 edges/thread, issued early
// consumed late -> hidden in idle latency), so k_agg's phase A needs no gathers at all.
__global__ __launch_bounds__(256) void k_bin(
    const int* __restrict__ ei, const float* __restrict__ alphas,
    int* __restrict__ bfill, int4* __restrict__ binned, int shift, int E){
  __shared__ int4 buf[2048];
  __shared__ int cnt[128], off[128], gbase[128];
  int tid = threadIdx.x;
  int c0 = blockIdx.x*2048;
  int m = min(2048, E - c0);
  if (m <= 0) return;
  for (int i=tid; i<128; i+=256) cnt[i] = 0;
  __syncthreads();
  int myb[8], myslot[8], mysrc[8], mydst[8];
  int myw0[8], myw1[8];
  #pragma unroll
  for (int j=0;j<8;++j){
    int k = tid + j*256;
    if (k < m){
      int e = c0 + k;
      int s = ei[e];
      mysrc[j] = s;
      mydst[j] = ei[E+e];
      float4 as = ((const float4*)alphas)[(size_t)s*2];   // src-side 4 alphas
      myw0[j] = (int)(((unsigned)bfr(as.x)) | (((unsigned)bfr(as.y))<<16));
      myw1[j] = (int)(((unsigned)bfr(as.z)) | (((unsigned)bfr(as.w))<<16));
      int bkt = mydst[j] >> shift;
      myb[j] = bkt;
      myslot[j] = atomicAdd(&cnt[bkt], 1);
    } else myb[j] = -1;
  }
  __syncthreads();
  if (tid == 0){
    int acc = 0;
    for (int i=0;i<128;++i){ off[i] = acc; acc += cnt[i]; }
  }
  __syncthreads();
  #pragma unroll
  for (int j=0;j<8;++j)
    if (myb[j] >= 0) buf[off[myb[j]] + myslot[j]] = make_int4(mysrc[j], mydst[j], myw0[j], myw1[j]);
  if (tid < 128 && cnt[tid] > 0) gbase[tid] = atomicAdd(&bfill[tid], cnt[tid]);
  __syncthreads();
  for (int i=tid; i<m; i+=256){
    int4 p = buf[i];
    int bkt = p.y >> shift;
    binned[gbase[bkt] + (i - off[bkt])] = p;
  }
}

// ---------------- phase B: per-bucket deg-count + LDS scan -> rowptr; place src + packed alphas.
__global__ __launch_bounds__(1024) void k_place(
    const int4* __restrict__ binned, const int* __restrict__ bbase,
    int* __restrict__ rowptr, int* __restrict__ csr_src, int2* __restrict__ csr_w,
    int shift, int N){
  __shared__ int cnt[1024];
  __shared__ int tsum[1024];
  int tid = threadIdx.x;
  int d0 = blockIdx.x << shift;
  if (d0 >= N) return;
  int dpb = 1 << shift;              // <= 1024
  int dlim = min(dpb, N - d0);
  if (tid < dpb) cnt[tid] = 0;
  __syncthreads();
  int base = bbase[blockIdx.x], end = bbase[blockIdx.x+1];
  for (int i = base + tid; i < end; i += 1024)
    atomicAdd(&cnt[binned[i].y - d0], 1);
  __syncthreads();
  int xv = (tid < dpb) ? cnt[tid] : 0;
  tsum[tid] = xv;
  __syncthreads();
  for (int off=1; off<1024; off<<=1){
    int t = (tid>=off) ? tsum[tid-off] : 0;
    __syncthreads();
    tsum[tid] += t;
    __syncthreads();
  }
  if (tid < dpb) cnt[tid] = tsum[tid] - xv + base;   // global rowptr values
  __syncthreads();
  if (tid < dlim) rowptr[d0+tid] = cnt[tid];
  __syncthreads();
  for (int i = base + tid; i < end; i += 1024){
    int4 p = binned[i];
    int pos = atomicAdd(&cnt[p.y - d0], 1);
    csr_src[pos] = p.x;
    csr_w[pos] = make_int2(p.z, p.w);
  }
}

// ---------------- per-dst softmax aggregation: phase A fully coalesced (no gathers),
// phase B int8 h row gather (the only per-edge gather), 4-way ILP.
__global__ __launch_bounds__(256) void k_agg(
    const int* __restrict__ csr_src, const int2* __restrict__ csr_w,
    const int* __restrict__ rowptr, const float* __restrict__ alphas,
    const signed char* __restrict__ h8, unsigned short* __restrict__ aggb, int N){
  __shared__ float4 wb4[4][64];
  __shared__ int    sb[4][64];
  int wave = threadIdx.x>>6, lane = threadIdx.x&63;
  int dst = blockIdx.x*4 + wave;
  if (dst >= N) return;
  int base = rowptr[dst];
  int d = rowptr[dst+1] - base;
  float4 ad = ((const float4*)alphas)[(size_t)dst*2+1];
  float ss0=0.f,ss1=0.f,ss2=0.f,ss3=0.f;
  float a0=0.f,a1=0.f,a2=0.f,a3=0.f;
  for (int c0=0; c0<d; c0+=64){
    int cnt = min(64, d-c0);
    if (lane < cnt){
      int s = csr_src[base+c0+lane];
      int2 wp = csr_w[base+c0+lane];
      float e0 = bf2f((unsigned short)(wp.x & 0xFFFF)) + ad.x; e0 = e0>0.f ? e0 : NEG_SLOPE*e0; float x0=__expf(e0); ss0+=x0;
      float e1 = bf2f((unsigned short)((unsigned)wp.x >> 16)) + ad.y; e1 = e1>0.f ? e1 : NEG_SLOPE*e1; float x1=__expf(e1); ss1+=x1;
      float e2 = bf2f((unsigned short)(wp.y & 0xFFFF)) + ad.z; e2 = e2>0.f ? e2 : NEG_SLOPE*e2; float x2=__expf(e2); ss2+=x2;
      float e3 = bf2f((unsigned short)((unsigned)wp.y >> 16)) + ad.w; e3 = e3>0.f ? e3 : NEG_SLOPE*e3; float x3=__expf(e3); ss3+=x3;
      sb[wave][lane] = s;
      wb4[wave][lane] = make_float4(x0,x1,x2,x3);
    }
    asm volatile("" ::: "memory");   // pin LDS write->read order (in-wave DS is in-order)
    int j = 0;
    for (; j+3 < cnt; j += 4){
      int s0_ = sb[wave][j],   s1_ = sb[wave][j+1];
      int s2_ = sb[wave][j+2], s3_ = sb[wave][j+3];
      float4 w0_ = wb4[wave][j],   w1_ = wb4[wave][j+1];
      float4 w2_ = wb4[wave][j+2], w3_ = wb4[wave][j+3];
      float h0_ = (float)h8[(size_t)s0_*64 + lane];
      float h1_ = (float)h8[(size_t)s1_*64 + lane];
      float h2_ = (float)h8[(size_t)s2_*64 + lane];
      float h3_ = (float)h8[(size_t)s3_*64 + lane];
      a0 += w0_.x*h0_; a1 += w0_.y*h0_; a2 += w0_.z*h0_; a3 += w0_.w*h0_;
      a0 += w1_.x*h1_; a1 += w1_.y*h1_; a2 += w1_.z*h1_; a3 += w1_.w*h1_;
      a0 += w2_.x*h2_; a1 += w2_.y*h2_; a2 += w2_.z*h2_; a3 += w2_.w*h2_;
      a0 += w3_.x*h3_; a1 += w3_.y*h3_; a2 += w3_.z*h3_; a3 += w3_.w*h3_;
    }
    for (; j < cnt; ++j){
      int sj = sb[wave][j];
      float4 wj = wb4[wave][j];
      float hv = (float)h8[(size_t)sj*64 + lane];
      a0 += wj.x*hv; a1 += wj.y*hv; a2 += wj.z*hv; a3 += wj.w*hv;
    }
    asm volatile("" ::: "memory");
  }
  #pragma unroll
  for (int off=32; off; off>>=1){
    ss0 += __shfl_xor(ss0, off, 64);
    ss1 += __shfl_xor(ss1, off, 64);
    ss2 += __shfl_xor(ss2, off, 64);
    ss3 += __shfl_xor(ss3, off, 64);
  }
  size_t o = (size_t)dst*64 + lane;
  size_t NE = (size_t)N*64;
  if (d>0){
    // h was quantized as q = h*128: fold the 1/128 into the normalization
    aggb[o]      = bfr(a0/(ss0*128.f));
    aggb[NE+o]   = bfr(a1/(ss1*128.f));
    aggb[2*NE+o] = bfr(a2/(ss2*128.f));
    aggb[3*NE+o] = bfr(a3/(ss3*128.f));
  } else {
    aggb[o] = 0; aggb[NE+o] = 0; aggb[2*NE+o] = 0; aggb[3*NE+o] = 0;
  }
}

// ---------------- fused dual-GEMM (MFMA bf16) + LSTM. Pl exchange in bf16 (17.4 KB LDS).
__global__ __launch_bounds__(256) void k_fused(
    const unsigned short* __restrict__ xb, const unsigned short* __restrict__ aggb,
    const unsigned short* __restrict__ pw, const unsigned short* __restrict__ ps,
    const float* __restrict__ b, const float* __restrict__ gat_b,
    const float* __restrict__ c, float* __restrict__ out, int N){
  __shared__ unsigned short Pl[4][32][68];
  int tid = threadIdx.x, g = tid>>6, l = tid&63;
  int lr = l & 15;
  int lq = l >> 4;
  int nbase = blockIdx.x*32;
  int nlim = min(32, N-nbase);

  s16x8 BW[2][4], BS[2][4];
  #pragma unroll
  for (int ks=0; ks<2; ++ks){
    #pragma unroll
    for (int ct=0; ct<4; ++ct){
      size_t idx = ((size_t)((g*2+ks)*4+ct)*64 + l)*8;
      BW[ks][ct] = *(const s16x8*)(pw + idx);
      BS[ks][ct] = *(const s16x8*)(ps + idx);
    }
  }

  s16x8 AX[2][2], AG[2][2];
  #pragma unroll
  for (int rt=0; rt<2; ++rt){
    int row = nbase + rt*16 + lr;
    if (row >= N) row = N-1;
    #pragma unroll
    for (int ks=0; ks<2; ++ks){
      AX[rt][ks] = *(const s16x8*)(xb   + (size_t)row*64 + ks*32 + lq*8);
      AG[rt][ks] = *(const s16x8*)(aggb + ((size_t)g*N + row)*64 + ks*32 + lq*8);
    }
  }

  #pragma unroll
  for (int rt=0; rt<2; ++rt){
    #pragma unroll
    for (int ct=0; ct<4; ++ct){
      int col = ct*16 + lr;
      float bias = b[g*64 + col] + gat_b[g*64 + col];
      f32x4 acc = {bias, bias, bias, bias};
      #pragma unroll
      for (int ks=0; ks<2; ++ks){
        acc = __builtin_amdgcn_mfma_f32_16x16x32_bf16(AX[rt][ks], BW[ks][ct], acc, 0,0,0);
        acc = __builtin_amdgcn_mfma_f32_16x16x32_bf16(AG[rt][ks], BS[ks][ct], acc, 0,0,0);
      }
      #pragma unroll
      for (int r=0;r<4;++r)
        Pl[g][rt*16 + lq*4 + r][col] = bfr(acc[r]);
    }
  }
  __syncthreads();

  size_t NE = (size_t)N*64;
  #pragma unroll
  for (int n=0; n<8; ++n){
    int node = g*8 + n;
    if (node < nlim){
      size_t o = (size_t)(nbase + node)*64 + l;
      float p0 = bf2f(Pl[0][node][l]);
      float p1 = bf2f(Pl[1][node][l]);
      float p2 = bf2f(Pl[2][node][l]);
      float p3 = bf2f(Pl[3][node][l]);
      float ig = 1.f/(1.f + __expf(-p0));
      float fg = 1.f/(1.f + __expf(-p1));
      float tg = tanhf(p2);
      float og = 1.f/(1.f + __expf(-p3));
      float cn = fg*c[o] + ig*tg;
      out[o]      = og*tanhf(cn);
      out[NE + o] = cn;
    }
  }
}

extern "C" void kernel_launch(void* const* d_in, const int* in_sizes, int n_in,
                              void* d_out, int out_size, void* d_ws, size_t ws_size,
                              hipStream_t stream){
  const float* x       = (const float*)d_in[0];
  const int*   ei      = (const int*)d_in[1];
  const float* h       = (const float*)d_in[2];
  const float* c       = (const float*)d_in[3];
  const float* W       = (const float*)d_in[4];
  const float* b       = (const float*)d_in[5];
  const float* Wsrc    = (const float*)d_in[6];
  const float* Wdst    = (const float*)d_in[7];
  const float* att_src = (const float*)d_in[8];
  const float* att_dst = (const float*)d_in[9];
  const float* gat_b   = (const float*)d_in[10];
  float* out = (float*)d_out;

  int N = in_sizes[0] / 64;
  int E = in_sizes[1] / 2;

  // bucket shift: nbuck <= 128, dst-per-bucket <= 1024 (LDS arrays)
  int shift = 9;
  while (((N + (1<<shift) - 1) >> shift) > 128) shift++;
  int nbuck = (N + (1<<shift) - 1) >> shift;

  unsigned short* aggb = (unsigned short*)d_ws;        // 4*N*64
  unsigned short* xb   = aggb + (size_t)4*N*64;        // N*64
  signed char*    h8   = (signed char*)(xb + (size_t)N*64);    // N*64 bytes
  unsigned short* pw   = (unsigned short*)(h8 + (size_t)N*64); // 16384
  unsigned short* ps   = pw   + 16384;                 // 16384
  float* alphas = (float*)(ps + 16384);                // N*8
  int* csr_src  = (int*)(alphas + (size_t)N*8);        // E
  int4* binned  = (int4*)(csr_src + ((E+3)&~3));       // E (16B each)
  int2* csr_w   = (int2*)(binned + E);                 // E (8B each)
  int* rowptr   = (int*)(csr_w + E);                   // N+1
  int* bcnt     = rowptr + N + 1;                      // 128
  int* bbase    = bcnt + 128;                          // 129
  int* bfill    = bbase + 129;                         // 128
  float* wvec   = (float*)(bfill + 128);               // 512

  k_wvec_pack<<<9, 512, 0, stream>>>(Wsrc, Wdst, W, att_src, att_dst, wvec, bcnt, pw, ps);
  k_pack  <<<(N+31)/32, 256, 0, stream>>>(x, h, wvec, ei, xb, h8, alphas, bcnt, shift, N, E);
  k_bscan <<<1, 128, 0, stream>>>(bcnt, bbase, bfill, rowptr, nbuck, N, E);
  k_bin   <<<(E + 2047)/2048, 256, 0, stream>>>(ei, alphas, bfill, binned, shift, E);
  k_place <<<nbuck, 1024, 0, stream>>>(binned, bbase, rowptr, csr_src, csr_w, shift, N);
  k_agg   <<<(N+3)/4, 256, 0, stream>>>(csr_src, csr_w, rowptr, alphas, h8, aggb, N);
  k_fused <<<(N+31)/32, 256, 0, stream>>>(xb, aggb, pw, ps, b, gat_b, c, out, N);
}

// Round 23
// 127.376 us; speedup vs baseline: 1.0910x; 1.0910x over previous
//
#include <hip/hip_runtime.h>
#include <math.h>

#define NEG_SLOPE 0.2f

typedef float  f32x4 __attribute__((ext_vector_type(4)));
typedef short  s16x8 __attribute__((ext_vector_type(8)));

__device__ __forceinline__ unsigned short bfr(float a){
  unsigned u = __float_as_uint(a);
  return (unsigned short)((u + 0x7FFFu + ((u>>16)&1u)) >> 16);
}
__device__ __forceinline__ float bf2f(unsigned short s){
  return __uint_as_float(((unsigned)s)<<16);
}
__device__ __forceinline__ ushort4 packf4(float4 v){
  ushort4 r; r.x=bfr(v.x); r.y=bfr(v.y); r.z=bfr(v.z); r.w=bfr(v.w); return r;
}

// f32 -> int8 linear, q = rint(v*128), clamp ±127 (|h| < 1 by construction)
__device__ __forceinline__ signed char q8(float v){
  int q = __float2int_rn(v * 128.f);
  q = q > 127 ? 127 : (q < -127 ? -127 : q);
  return (signed char)q;
}

// ---------------- block 0: wvec + zero bcnt; blocks 1-8: weight pre-pack (B-frag order)
__global__ void k_wvec_pack(const float* __restrict__ Wsrc, const float* __restrict__ Wdst,
                            const float* __restrict__ Wmain,
                            const float* __restrict__ att_src, const float* __restrict__ att_dst,
                            float* __restrict__ wvec, int* __restrict__ bcnt,
                            unsigned short* __restrict__ pw, unsigned short* __restrict__ ps){
  int tid = threadIdx.x;           // 512 threads
  if (blockIdx.x == 0){
    if (tid < 128) bcnt[tid] = 0;
    int v = tid >> 6, t = tid & 63;
    const float* M = (v<4) ? (Wsrc + v*4096) : (Wdst + (v-4)*4096);
    const float* a = (v<4) ? (att_src + v*64) : (att_dst + (v-4)*64);
    float s = 0.f;
    for (int k=0;k<64;++k) s += M[t*64+k]*a[k];
    wvec[v*64+t] = s;
  } else {
    int vv = (blockIdx.x-1)*512 + tid;     // 4096 slots, 2048 jobs
    if (vv < 2048){
      int l = vv & 63, u = vv >> 6;
      int ct = u & 3, ks = (u>>2)&1, g = u>>3;
      int col = ct*16 + (l&15);
      int r0  = ks*32 + (l>>4)*8;
      #pragma unroll
      for (int j=0;j<8;++j){
        pw[vv*8+j] = bfr(Wmain[g*4096 + (r0+j)*64 + col]);
        ps[vv*8+j] = bfr(Wsrc [g*4096 + (r0+j)*64 + col]);
      }
    }
  }
}

// ---------------- pack x->bf16, h->int8; alphas = h.wvec[v]; + fused BUCKET histogram
__global__ __launch_bounds__(256) void k_pack(
    const float* __restrict__ x, const float* __restrict__ h,
    const float* __restrict__ wvec, const int* __restrict__ ei,
    unsigned short* __restrict__ xb, signed char* __restrict__ h8,
    float* __restrict__ alphas, int* __restrict__ bcnt, int shift, int N, int E){
  __shared__ float hl[32*65];
  __shared__ float wl[8*65];
  __shared__ int   cb[128];
  int tid = threadIdx.x;
  int nbase = blockIdx.x*32;
  int nlim = min(32, N-nbase);
  int cnt = nlim*16;
  if (tid < 128) cb[tid] = 0;
  {
    const float4* hsrc = (const float4*)(h + (size_t)nbase*64);
    const float4* xsrc = (const float4*)(x + (size_t)nbase*64);
    char4* hdst = (char4*)(h8 + (size_t)nbase*64);
    ushort4* xdst = (ushort4*)(xb + (size_t)nbase*64);
    for (int i=tid; i<cnt; i+=256){
      float4 v = hsrc[i];
      int n = i>>4, t4 = (i&15)*4;
      float* d = hl + n*65 + t4;
      d[0]=v.x; d[1]=v.y; d[2]=v.z; d[3]=v.w;
      hdst[i] = make_char4(q8(v.x), q8(v.y), q8(v.z), q8(v.w));
      xdst[i] = packf4(xsrc[i]);
    }
    for (int i=tid; i<512; i+=256) wl[(i>>6)*65 + (i&63)] = wvec[i];
  }
  __syncthreads();
  int v = tid & 7, n = tid >> 3;     // 32 rows x 8 vecs
  if (n < nlim){
    const float* hp = hl + n*65;
    const float* wp = wl + v*65;
    float s = 0.f;
    #pragma unroll
    for (int t=0;t<64;++t) s += hp[t]*wp[t];
    alphas[(size_t)(nbase+n)*8 + v] = s;
  }
  // ---- fused bucket histogram (LDS-privatized, 128 global atomics per block)
  int Q = E >> 2;
  const int4* d4 = (const int4*)(ei + E);
  long gs = (long)gridDim.x*256;
  for (long q=(long)blockIdx.x*256+tid; q<Q; q+=gs){
    int4 d = d4[q];
    atomicAdd(&cb[d.x>>shift],1); atomicAdd(&cb[d.y>>shift],1);
    atomicAdd(&cb[d.z>>shift],1); atomicAdd(&cb[d.w>>shift],1);
  }
  int tail = E - (Q<<2);
  if (blockIdx.x == 0 && tid < tail) atomicAdd(&cb[ei[E+(Q<<2)+tid]>>shift],1);
  __syncthreads();
  if (tid < 128 && cb[tid]) atomicAdd(&bcnt[tid], cb[tid]);
}

// ---------------- scan <=128 bucket counts -> bbase + bfill cursors
__global__ void k_bscan(const int* __restrict__ bcnt, int* __restrict__ bbase,
                        int* __restrict__ bfill, int* __restrict__ rowptr,
                        int nbuck, int N, int E){
  __shared__ int s[128];
  int tid = threadIdx.x;             // 128 threads
  int x = (tid<nbuck) ? bcnt[tid] : 0;
  s[tid] = x;
  __syncthreads();
  for (int off=1; off<128; off<<=1){
    int t = (tid>=off) ? s[tid-off] : 0;
    __syncthreads();
    s[tid] += t;
    __syncthreads();
  }
  if (tid<nbuck){ int e = s[tid]-x; bbase[tid]=e; bfill[tid]=e; }
  if (tid==0){ bbase[nbuck]=E; rowptr[N]=E; }
}

// ---------------- phase A: LDS-binned coarse sort of edges by dst bucket.
__global__ __launch_bounds__(256) void k_bin(
    const int* __restrict__ ei, int* __restrict__ bfill,
    int2* __restrict__ binned, int shift, int E){
  __shared__ int2 buf[2048];
  __shared__ int cnt[128], off[128], gbase[128];
  int tid = threadIdx.x;
  int c0 = blockIdx.x*2048;
  int m = min(2048, E - c0);
  if (m <= 0) return;
  for (int i=tid; i<128; i+=256) cnt[i] = 0;
  __syncthreads();
  int myb[8], myslot[8], mysrc[8], mydst[8];
  #pragma unroll
  for (int j=0;j<8;++j){
    int k = tid + j*256;
    if (k < m){
      int e = c0 + k;
      mysrc[j] = ei[e];
      mydst[j] = ei[E+e];
      int bkt = mydst[j] >> shift;
      myb[j] = bkt;
      myslot[j] = atomicAdd(&cnt[bkt], 1);
    } else myb[j] = -1;
  }
  __syncthreads();
  if (tid == 0){
    int acc = 0;
    for (int i=0;i<128;++i){ off[i] = acc; acc += cnt[i]; }
  }
  __syncthreads();
  #pragma unroll
  for (int j=0;j<8;++j)
    if (myb[j] >= 0) buf[off[myb[j]] + myslot[j]] = make_int2(mysrc[j], mydst[j]);
  if (tid < 128 && cnt[tid] > 0) gbase[tid] = atomicAdd(&bfill[tid], cnt[tid]);
  __syncthreads();
  for (int i=tid; i<m; i+=256){
    int2 p = buf[i];
    int bkt = p.y >> shift;
    binned[gbase[bkt] + (i - off[bkt])] = p;
  }
}

// ---------------- phase B: per-bucket deg-count + LDS scan -> rowptr slice; then place.
__global__ __launch_bounds__(1024) void k_place(
    const int2* __restrict__ binned, const int* __restrict__ bbase,
    int* __restrict__ rowptr, int* __restrict__ csr_src, int shift, int N){
  __shared__ int cnt[1024];
  __shared__ int tsum[1024];
  int tid = threadIdx.x;
  int d0 = blockIdx.x << shift;
  if (d0 >= N) return;
  int dpb = 1 << shift;              // <= 1024
  int dlim = min(dpb, N - d0);
  if (tid < dpb) cnt[tid] = 0;
  __syncthreads();
  int base = bbase[blockIdx.x], end = bbase[blockIdx.x+1];
  for (int i = base + tid; i < end; i += 1024)
    atomicAdd(&cnt[binned[i].y - d0], 1);
  __syncthreads();
  int xv = (tid < dpb) ? cnt[tid] : 0;
  tsum[tid] = xv;
  __syncthreads();
  for (int off=1; off<1024; off<<=1){
    int t = (tid>=off) ? tsum[tid-off] : 0;
    __syncthreads();
    tsum[tid] += t;
    __syncthreads();
  }
  if (tid < dpb) cnt[tid] = tsum[tid] - xv + base;   // global rowptr values
  __syncthreads();
  if (tid < dlim) rowptr[d0+tid] = cnt[tid];
  __syncthreads();
  for (int i = base + tid; i < end; i += 1024){
    int2 p = binned[i];
    int pos = atomicAdd(&cnt[p.y - d0], 1);
    csr_src[pos] = p.x;
  }
}

// ---------------- per-dst softmax aggregation: int8 h gather (1 cvt decode), 4-way ILP
__global__ __launch_bounds__(256) void k_agg(
    const int* __restrict__ csr_src, const int* __restrict__ rowptr,
    const float* __restrict__ alphas,
    const signed char* __restrict__ h8, unsigned short* __restrict__ aggb, int N){
  __shared__ float4 wb4[4][64];
  __shared__ int    sb[4][64];
  int wave = threadIdx.x>>6, lane = threadIdx.x&63;
  int dst = blockIdx.x*4 + wave;
  if (dst >= N) return;
  int base = rowptr[dst];
  int d = rowptr[dst+1] - base;
  float4 ad = ((const float4*)alphas)[(size_t)dst*2+1];
  float ss0=0.f,ss1=0.f,ss2=0.f,ss3=0.f;
  float a0=0.f,a1=0.f,a2=0.f,a3=0.f;
  for (int c0=0; c0<d; c0+=64){
    int cnt = min(64, d-c0);
    if (lane < cnt){
      int s = csr_src[base+c0+lane];
      float4 as = ((const float4*)alphas)[(size_t)s*2];
      float e0=as.x+ad.x; e0 = e0>0.f ? e0 : NEG_SLOPE*e0; float x0=__expf(e0); ss0+=x0;
      float e1=as.y+ad.y; e1 = e1>0.f ? e1 : NEG_SLOPE*e1; float x1=__expf(e1); ss1+=x1;
      float e2=as.z+ad.z; e2 = e2>0.f ? e2 : NEG_SLOPE*e2; float x2=__expf(e2); ss2+=x2;
      float e3=as.w+ad.w; e3 = e3>0.f ? e3 : NEG_SLOPE*e3; float x3=__expf(e3); ss3+=x3;
      sb[wave][lane] = s;
      wb4[wave][lane] = make_float4(x0,x1,x2,x3);
    }
    asm volatile("" ::: "memory");   // pin LDS write->read order (in-wave DS is in-order)
    int j = 0;
    for (; j+3 < cnt; j += 4){
      int s0_ = sb[wave][j],   s1_ = sb[wave][j+1];
      int s2_ = sb[wave][j+2], s3_ = sb[wave][j+3];
      float4 w0_ = wb4[wave][j],   w1_ = wb4[wave][j+1];
      float4 w2_ = wb4[wave][j+2], w3_ = wb4[wave][j+3];
      float h0_ = (float)h8[(size_t)s0_*64 + lane];
      float h1_ = (float)h8[(size_t)s1_*64 + lane];
      float h2_ = (float)h8[(size_t)s2_*64 + lane];
      float h3_ = (float)h8[(size_t)s3_*64 + lane];
      a0 += w0_.x*h0_; a1 += w0_.y*h0_; a2 += w0_.z*h0_; a3 += w0_.w*h0_;
      a0 += w1_.x*h1_; a1 += w1_.y*h1_; a2 += w1_.z*h1_; a3 += w1_.w*h1_;
      a0 += w2_.x*h2_; a1 += w2_.y*h2_; a2 += w2_.z*h2_; a3 += w2_.w*h2_;
      a0 += w3_.x*h3_; a1 += w3_.y*h3_; a2 += w3_.z*h3_; a3 += w3_.w*h3_;
    }
    for (; j < cnt; ++j){
      int sj = sb[wave][j];
      float4 wj = wb4[wave][j];
      float hv = (float)h8[(size_t)sj*64 + lane];
      a0 += wj.x*hv; a1 += wj.y*hv; a2 += wj.z*hv; a3 += wj.w*hv;
    }
    asm volatile("" ::: "memory");
  }
  #pragma unroll
  for (int off=32; off; off>>=1){
    ss0 += __shfl_xor(ss0, off, 64);
    ss1 += __shfl_xor(ss1, off, 64);
    ss2 += __shfl_xor(ss2, off, 64);
    ss3 += __shfl_xor(ss3, off, 64);
  }
  size_t o = (size_t)dst*64 + lane;
  size_t NE = (size_t)N*64;
  if (d>0){
    // h was quantized as q = h*128: fold the 1/128 into the normalization
    aggb[o]      = bfr(a0/(ss0*128.f));
    aggb[NE+o]   = bfr(a1/(ss1*128.f));
    aggb[2*NE+o] = bfr(a2/(ss2*128.f));
    aggb[3*NE+o] = bfr(a3/(ss3*128.f));
  } else {
    aggb[o] = 0; aggb[NE+o] = 0; aggb[2*NE+o] = 0; aggb[3*NE+o] = 0;
  }
}

// ---------------- fused dual-GEMM (MFMA bf16) + LSTM. Pl exchange in bf16 (17.4 KB LDS).
__global__ __launch_bounds__(256) void k_fused(
    const unsigned short* __restrict__ xb, const unsigned short* __restrict__ aggb,
    const unsigned short* __restrict__ pw, const unsigned short* __restrict__ ps,
    const float* __restrict__ b, const float* __restrict__ gat_b,
    const float* __restrict__ c, float* __restrict__ out, int N){
  __shared__ unsigned short Pl[4][32][68];
  int tid = threadIdx.x, g = tid>>6, l = tid&63;
  int lr = l & 15;
  int lq = l >> 4;
  int nbase = blockIdx.x*32;
  int nlim = min(32, N-nbase);

  s16x8 BW[2][4], BS[2][4];
  #pragma unroll
  for (int ks=0; ks<2; ++ks){
    #pragma unroll
    for (int ct=0; ct<4; ++ct){
      size_t idx = ((size_t)((g*2+ks)*4+ct)*64 + l)*8;
      BW[ks][ct] = *(const s16x8*)(pw + idx);
      BS[ks][ct] = *(const s16x8*)(ps + idx);
    }
  }

  s16x8 AX[2][2], AG[2][2];
  #pragma unroll
  for (int rt=0; rt<2; ++rt){
    int row = nbase + rt*16 + lr;
    if (row >= N) row = N-1;
    #pragma unroll
    for (int ks=0; ks<2; ++ks){
      AX[rt][ks] = *(const s16x8*)(xb   + (size_t)row*64 + ks*32 + lq*8);
      AG[rt][ks] = *(const s16x8*)(aggb + ((size_t)g*N + row)*64 + ks*32 + lq*8);
    }
  }

  #pragma unroll
  for (int rt=0; rt<2; ++rt){
    #pragma unroll
    for (int ct=0; ct<4; ++ct){
      int col = ct*16 + lr;
      float bias = b[g*64 + col] + gat_b[g*64 + col];
      f32x4 acc = {bias, bias, bias, bias};
      #pragma unroll
      for (int ks=0; ks<2; ++ks){
        acc = __builtin_amdgcn_mfma_f32_16x16x32_bf16(AX[rt][ks], BW[ks][ct], acc, 0,0,0);
        acc = __builtin_amdgcn_mfma_f32_16x16x32_bf16(AG[rt][ks], BS[ks][ct], acc, 0,0,0);
      }
      #pragma unroll
      for (int r=0;r<4;++r)
        Pl[g][rt*16 + lq*4 + r][col] = bfr(acc[r]);
    }
  }
  __syncthreads();

  size_t NE = (size_t)N*64;
  #pragma unroll
  for (int n=0; n<8; ++n){
    int node = g*8 + n;
    if (node < nlim){
      size_t o = (size_t)(nbase + node)*64 + l;
      float p0 = bf2f(Pl[0][node][l]);
      float p1 = bf2f(Pl[1][node][l]);
      float p2 = bf2f(Pl[2][node][l]);
      float p3 = bf2f(Pl[3][node][l]);
      float ig = 1.f/(1.f + __expf(-p0));
      float fg = 1.f/(1.f + __expf(-p1));
      float tg = tanhf(p2);
      float og = 1.f/(1.f + __expf(-p3));
      float cn = fg*c[o] + ig*tg;
      out[o]      = og*tanhf(cn);
      out[NE + o] = cn;
    }
  }
}

extern "C" void kernel_launch(void* const* d_in, const int* in_sizes, int n_in,
                              void* d_out, int out_size, void* d_ws, size_t ws_size,
                              hipStream_t stream){
  const float* x       = (const float*)d_in[0];
  const int*   ei      = (const int*)d_in[1];
  const float* h       = (const float*)d_in[2];
  const float* c       = (const float*)d_in[3];
  const float* W       = (const float*)d_in[4];
  const float* b       = (const float*)d_in[5];
  const float* Wsrc    = (const float*)d_in[6];
  const float* Wdst    = (const float*)d_in[7];
  const float* att_src = (const float*)d_in[8];
  const float* att_dst = (const float*)d_in[9];
  const float* gat_b   = (const float*)d_in[10];
  float* out = (float*)d_out;

  int N = in_sizes[0] / 64;
  int E = in_sizes[1] / 2;

  // bucket shift: nbuck <= 128, dst-per-bucket <= 1024 (LDS arrays)
  int shift = 9;
  while (((N + (1<<shift) - 1) >> shift) > 128) shift++;
  int nbuck = (N + (1<<shift) - 1) >> shift;

  unsigned short* aggb = (unsigned short*)d_ws;        // 4*N*64
  unsigned short* xb   = aggb + (size_t)4*N*64;        // N*64
  signed char*    h8   = (signed char*)(xb + (size_t)N*64);    // N*64 bytes
  unsigned short* pw   = (unsigned short*)(h8 + (size_t)N*64); // 16384
  unsigned short* ps   = pw   + 16384;                 // 16384
  float* alphas = (float*)(ps + 16384);                // N*8
  int* csr_src  = (int*)(alphas + (size_t)N*8);        // E
  int2* binned  = (int2*)(csr_src + ((E+3)&~3));       // E (8B aligned)
  int* rowptr   = (int*)(binned + E);                  // N+1
  int* bcnt     = rowptr + N + 1;                      // 128
  int* bbase    = bcnt + 128;                          // 129
  int* bfill    = bbase + 129;                         // 128
  float* wvec   = (float*)(bfill + 128);               // 512

  k_wvec_pack<<<9, 512, 0, stream>>>(Wsrc, Wdst, W, att_src, att_dst, wvec, bcnt, pw, ps);
  k_pack  <<<(N+31)/32, 256, 0, stream>>>(x, h, wvec, ei, xb, h8, alphas, bcnt, shift, N, E);
  k_bscan <<<1, 128, 0, stream>>>(bcnt, bbase, bfill, rowptr, nbuck, N, E);
  k_bin   <<<(E + 2047)/2048, 256, 0, stream>>>(ei, bfill, binned, shift, E);
  k_place <<<nbuck, 1024, 0, stream>>>(binned, bbase, rowptr, csr_src, shift, N);
  k_agg   <<<(N+3)/4, 256, 0, stream>>>(csr_src, rowptr, alphas, h8, aggb, N);
  k_fused <<<(N+31)/32, 256, 0, stream>>>(xb, aggb, pw, ps, b, gat_b, c, out, N);
}